// Round 16
// baseline (935.051 us; speedup 1.0000x reference)
//
#include <hip/hip_runtime.h>
#include <math.h>

// ---------------------------------------------------------------------------
// IsgnBeatMeasEncoder — round 20: overlap A-load and B-DMA in gemm staging.
// Round-19: gather de-chain = 952 -> 919 (matched, 5th straight). Still
// latency-bound (VALU 0.25%, HBM 0.05%).
// gemm staging mechanism: current order A-load(issue->WAIT->ds_write) then
// B global_load_lds then barrier => the A-wait retires BEFORE B is issued;
// step = A-lat + B-lat (~1000cy). vmcnt is in-order, so issuing B DMAs FIRST
// and then the A load makes the A-wait drain BOTH concurrently:
// step = max(A,B) (~550cy). Pure issue-order change, no sync semantics.
// ~450cy x 8-12 steps x 11 calls ~= 25-35us.
// All else frozen (rec64 @116us latency floor, VGPR-132 canary).
// Falsification: total >=912 -> compiler already hoisted / staging not the
// bottleneck; declare practical plateau.
// ---------------------------------------------------------------------------

#define NN    1024
#define EE    10
#define INDIM 78
#define SS    320
#define SECD  128
#define NB    256
#define NM    64
#define CAP   64     // max nonzeros per adjacency column (mean ~10.2)

typedef float v2f __attribute__((ext_vector_type(2)));

__device__ __forceinline__ void pkfma(v2f& a, v2f x, v2f y){
    asm("v_pk_fma_f32 %0, %1, %2, %0" : "+v"(a) : "v"(x), "v"(y));
}
// a.lo += x.lo*b.lo ; a.hi += x.hi*b.lo   (broadcast LOW half of b)
__device__ __forceinline__ void pkfma_blo(v2f& a, v2f x, v2f b){
    asm("v_pk_fma_f32 %0, %1, %2, %0 op_sel:[0,0,0] op_sel_hi:[1,0,1]"
        : "+v"(a) : "v"(x), "v"(b));
}
// a.lo += x.lo*b.hi ; a.hi += x.hi*b.hi   (broadcast HIGH half of b)
__device__ __forceinline__ void pkfma_bhi(v2f& a, v2f x, v2f b){
    asm("v_pk_fma_f32 %0, %1, %2, %0 op_sel:[0,1,0] op_sel_hi:[1,1,1]"
        : "+v"(a) : "v"(x), "v"(b));
}

#define LO2(F) ((v2f){F.x, F.y})
#define HI2(F) ((v2f){F.z, F.w})

__device__ __forceinline__ float fsig(float x){
    return __builtin_amdgcn_rcpf(1.f + __expf(-x));
}
__device__ __forceinline__ float ftanh(float x){
    // tanh(x) = 1 - 2/(exp(2x)+1); exp overflow -> inf -> rcp -> 0 -> 1 (correct)
    return 1.f - 2.f*__builtin_amdgcn_rcpf(1.f + __expf(2.f*x));
}

// ---------------- note_fc: x0 = tanh(nodes @ W + b); nh = [0(192) | x0] ------------
__global__ void k_note_fc(const float* __restrict__ nodes, const float* __restrict__ W,
                          const float* __restrict__ b, float* __restrict__ nh){
    int n = blockIdx.x, s = threadIdx.x;           // 128 threads
    __shared__ float xrow[INDIM];
    if (s < INDIM) xrow[s] = nodes[n*INDIM + s];
    __syncthreads();
    float acc = b[s];
    for (int k = 0; k < INDIM; ++k) acc += xrow[k]*W[k*128 + s];
    nh[n*SS + 192 + s] = ftanh(acc);
    nh[n*SS + s] = 0.f;
    if (s < 64) nh[n*SS + 128 + s] = 0.f;
}

// ---------------- CSR build: float4 scan of each adj row ---------------------------
__global__ void k_csr_build(const float* __restrict__ adj, int* __restrict__ cnt,
                            int* __restrict__ idx){
    int em = blockIdx.x;                   // e*NN + m  (row of adj[e])
    int e = em / NN, m = em % NN;
    const float4* row4 = (const float4*)(adj + (size_t)em * NN);
    int q = threadIdx.x;                   // 256 threads, 256 float4 = 1024 cols
    float4 v = row4[q];
    int n0 = q*4;
    if (v.x != 0.f){ int p = atomicAdd(&cnt[e*NN + n0+0], 1); if (p < CAP) idx[((size_t)e*NN + n0+0)*CAP + p] = m; }
    if (v.y != 0.f){ int p = atomicAdd(&cnt[e*NN + n0+1], 1); if (p < CAP) idx[((size_t)e*NN + n0+1)*CAP + p] = m; }
    if (v.z != 0.f){ int p = atomicAdd(&cnt[e*NN + n0+2], 1); if (p < CAP) idx[((size_t)e*NN + n0+2)*CAP + p] = m; }
    if (v.w != 0.f){ int p = atomicAdd(&cnt[e*NN + n0+3], 1); if (p < CAP) idx[((size_t)e*NN + n0+3)*CAP + p] = m; }
}

// ---------------- full gather (320 cols): LDS list cache + 4-way prefetch ----------
// 4 en/block, 320 threads (80 quads per en).
__global__ void k_gather_full(const float* __restrict__ x, const int* __restrict__ cnt,
                              const int* __restrict__ idx, float* __restrict__ act){
    int tid = threadIdx.x;
    int eg = tid / 80;                     // en group 0..3
    int q  = tid % 80;
    int en = blockIdx.x*4 + eg;
    __shared__ int lst_l[4][CAP];
    int c = cnt[en]; if (c > CAP) c = CAP; // same addr per group -> broadcast
    for (int j = q; j < c; j += 80) lst_l[eg][j] = idx[(size_t)en*CAP + j];
    __syncthreads();
    float4 acc = {0.f,0.f,0.f,0.f};
    const float* xb = x + q*4;
    int j = 0;
    for (; j + 4 <= c; j += 4){            // 4 independent loads in flight
        int m0=lst_l[eg][j], m1=lst_l[eg][j+1], m2=lst_l[eg][j+2], m3=lst_l[eg][j+3];
        float4 v0 = *(const float4*)(xb + (size_t)m0*SS);
        float4 v1 = *(const float4*)(xb + (size_t)m1*SS);
        float4 v2 = *(const float4*)(xb + (size_t)m2*SS);
        float4 v3 = *(const float4*)(xb + (size_t)m3*SS);
        acc.x += (v0.x+v1.x)+(v2.x+v3.x);
        acc.y += (v0.y+v1.y)+(v2.y+v3.y);
        acc.z += (v0.z+v1.z)+(v2.z+v3.z);
        acc.w += (v0.w+v1.w)+(v2.w+v3.w);
    }
    for (; j < c; ++j){
        float4 v = *(const float4*)(xb + (size_t)lst_l[eg][j]*SS);
        acc.x += v.x; acc.y += v.y; acc.z += v.z; acc.w += v.w;
    }
    *(float4*)(act + (size_t)en*SS + q*4) = acc;
}

// ---------------- dyn gather (cols 192..320): LDS list cache + 4-way prefetch ------
// 8 en/block, 256 threads (32 quads per en).
__global__ void k_gather_dyn(const float* __restrict__ x, const int* __restrict__ cnt,
                             const int* __restrict__ idx, float* __restrict__ act){
    int tid = threadIdx.x;
    int eg = tid >> 5;                     // en group 0..7
    int q  = tid & 31;
    int en = blockIdx.x*8 + eg;
    __shared__ int lst_l[8][CAP];
    int c = cnt[en]; if (c > CAP) c = CAP;
    for (int j = q; j < c; j += 32) lst_l[eg][j] = idx[(size_t)en*CAP + j];
    __syncthreads();
    float4 acc = {0.f,0.f,0.f,0.f};
    const float* xb = x + 192 + q*4;
    int j = 0;
    for (; j + 4 <= c; j += 4){
        int m0=lst_l[eg][j], m1=lst_l[eg][j+1], m2=lst_l[eg][j+2], m3=lst_l[eg][j+3];
        float4 v0 = *(const float4*)(xb + (size_t)m0*SS);
        float4 v1 = *(const float4*)(xb + (size_t)m1*SS);
        float4 v2 = *(const float4*)(xb + (size_t)m2*SS);
        float4 v3 = *(const float4*)(xb + (size_t)m3*SS);
        acc.x += (v0.x+v1.x)+(v2.x+v3.x);
        acc.y += (v0.y+v1.y)+(v2.y+v3.y);
        acc.z += (v0.z+v1.z)+(v2.z+v3.z);
        acc.w += (v0.w+v1.w)+(v2.w+v3.w);
    }
    for (; j < c; ++j){
        float4 v = *(const float4*)(xb + (size_t)lst_l[eg][j]*SS);
        acc.x += v.x; acc.y += v.y; acc.z += v.z; acc.w += v.w;
    }
    *(float4*)(act + (size_t)en*SS + 192 + q*4) = acc;
}

// ---------------- gate GEMM core (runtime K range) ---------------------------------
// Staging order: issue B's 4 global_load_lds DMAs FIRST, then the A global
// load. vmcnt is in-order, so the A-wait drains A and B concurrently:
// step = max(A,B) lat, not A+B.
__device__ __forceinline__ void gemm_body(const float* __restrict__ act,
        const float* __restrict__ W, float* __restrict__ outp,
        const float* __restrict__ addv, int K0, int K1, int nt, int z,
        float* A, float* B){
    int tid = threadIdx.x;
    int tx = tid & 31;             // cols tx*4 .. +3
    int ty = tid >> 5;             // rows ty*4 .. +3
    v2f acc[2][4];
    #pragma unroll
    for (int i=0;i<2;i++)
        #pragma unroll
        for (int j=0;j<4;j++) acc[i][j] = (v2f){0.f,0.f};
    for (int eh = 0; eh < 2; ++eh){
        int e = z*2 + eh;
        const float* Ae = act + (size_t)e*NN*SS + (size_t)nt*32*SS;
        const float* We = W   + (size_t)e*SS*SECD;
        for (int kc = K0; kc < K1; kc += 32){
            #pragma unroll
            for (int i=0;i<4;i++){                 // B DMAs FIRST (in flight)
                int lin4 = tid + i*256;            // float4 index; linear in LDS
                __builtin_amdgcn_global_load_lds(
                    (const __attribute__((address_space(1))) unsigned int*)
                        (We + (size_t)kc*SECD + (size_t)lin4*4),
                    (__attribute__((address_space(3))) unsigned int*)(B + lin4*4),
                    16, 0, 0);
            }
            {                                      // A load drains A+B together
                int r  = tid >> 3;
                int k4 = (tid & 7) << 2;
                float4 v = *(const float4*)(Ae + r*SS + kc + k4);
                A[(k4+0)*36 + r] = v.x; A[(k4+1)*36 + r] = v.y;
                A[(k4+2)*36 + r] = v.z; A[(k4+3)*36 + r] = v.w;
            }
            __syncthreads();                       // residual drain + A writes
            #pragma unroll 8
            for (int k=0;k<32;k++){
                float4 a4 = *(const float4*)(A + k*36 + ty*4);   // wave-uniform b128
                v2f a01 = LO2(a4), a23 = HI2(a4);
                float4 b = *(const float4*)(B + k*128 + tx*4);
                v2f b01 = {b.x, b.y}, b23 = {b.z, b.w};
                pkfma_blo(acc[0][0], a01, b01); pkfma_bhi(acc[0][1], a01, b01);
                pkfma_blo(acc[0][2], a01, b23); pkfma_bhi(acc[0][3], a01, b23);
                pkfma_blo(acc[1][0], a23, b01); pkfma_bhi(acc[1][1], a23, b01);
                pkfma_blo(acc[1][2], a23, b23); pkfma_bhi(acc[1][3], a23, b23);
            }
            __syncthreads();
        }
    }
    size_t base = ((size_t)z*NN + (size_t)nt*32)*384;   // +g*SECD folded by caller
    float* P = outp + base;
    int r0 = ty*4;
    float4 o0 = make_float4(acc[0][0].x, acc[0][1].x, acc[0][2].x, acc[0][3].x);
    float4 o1 = make_float4(acc[0][0].y, acc[0][1].y, acc[0][2].y, acc[0][3].y);
    float4 o2 = make_float4(acc[1][0].x, acc[1][1].x, acc[1][2].x, acc[1][3].x);
    float4 o3 = make_float4(acc[1][0].y, acc[1][1].y, acc[1][2].y, acc[1][3].y);
    if (addv){
        const float* Q = addv + base;
        float4 q0 = *(const float4*)(Q + (size_t)(r0+0)*384 + tx*4);
        float4 q1 = *(const float4*)(Q + (size_t)(r0+1)*384 + tx*4);
        float4 q2 = *(const float4*)(Q + (size_t)(r0+2)*384 + tx*4);
        float4 q3 = *(const float4*)(Q + (size_t)(r0+3)*384 + tx*4);
        o0.x+=q0.x; o0.y+=q0.y; o0.z+=q0.z; o0.w+=q0.w;
        o1.x+=q1.x; o1.y+=q1.y; o1.z+=q1.z; o1.w+=q1.w;
        o2.x+=q2.x; o2.y+=q2.y; o2.z+=q2.z; o2.w+=q2.w;
        o3.x+=q3.x; o3.y+=q3.y; o3.z+=q3.z; o3.w+=q3.w;
    }
    *(float4*)(P + (size_t)(r0+0)*384 + tx*4) = o0;
    *(float4*)(P + (size_t)(r0+1)*384 + tx*4) = o1;
    *(float4*)(P + (size_t)(r0+2)*384 + tx*4) = o2;
    *(float4*)(P + (size_t)(r0+3)*384 + tx*4) = o3;
}

// dyn-only (with optional addv fold): grid (32,3,5)
__global__ __launch_bounds__(256) void k_gate_gemm_dyn(const float* __restrict__ act,
        const float* __restrict__ wz, const float* __restrict__ wr,
        const float* __restrict__ wh, float* __restrict__ part,
        const float* __restrict__ addv){
    __shared__ float A[32*36];
    __shared__ float B[32*128];
    int g = blockIdx.y;
    const float* W = (g==0) ? wz : ((g==1) ? wr : wh);
    const float* av = addv ? (addv + g*SECD) : nullptr;
    gemm_body(act, W, part + g*SECD, av, 192, 320, blockIdx.x, blockIdx.z, A, B);
}

// merged it=0: static (y<3 -> part_s, K 0..192) + dyn (y>=3 -> part, K 192..320),
// grid (32,6,5), no addv (gru reads 10 slices this iteration).
__global__ __launch_bounds__(256) void k_gate_gemm_both(const float* __restrict__ act,
        const float* __restrict__ wz, const float* __restrict__ wr,
        const float* __restrict__ wh, float* __restrict__ part,
        float* __restrict__ part_s){
    __shared__ float A[32*36];
    __shared__ float B[32*128];
    int y = blockIdx.y;            // 0..5
    int g = (y >= 3) ? (y - 3) : y;
    const float* W = (g==0) ? wz : ((g==1) ? wr : wh);
    if (y >= 3)
        gemm_body(act, W, part   + g*SECD, nullptr, 192, 320, blockIdx.x, blockIdx.z, A, B);
    else
        gemm_body(act, W, part_s + g*SECD, nullptr,   0, 192, blockIdx.x, blockIdx.z, A, B);
}

// ---------------- GRU update v3: 512 thr, 2 notes, k split across 4 quarters -------
__global__ __launch_bounds__(512) void k_gru(float* __restrict__ x,
        const float* __restrict__ part, int nsp,
        const float* __restrict__ uz, const float* __restrict__ ur, const float* __restrict__ uh,
        const float* __restrict__ bz, const float* __restrict__ br, const float* __restrict__ bh){
    int n0 = blockIdx.x*2;
    int tid = threadIdx.x;
    int s  = tid & 127;                // col
    int qh = tid >> 7;                 // quarter (wave-uniform)
    int k0 = qh*32;
    __shared__ float xs[2][SECD], rx[2][SECD];
    __shared__ float redz[4][2][SECD], redr[4][2][SECD];   // redz reused for dh
    __shared__ float redm[2][3][2][SECD];                  // [half][gate][note][col]
    if (qh == 0){
        xs[0][s] = x[(n0+0)*SS + 192 + s];
        xs[1][s] = x[(n0+1)*SS + 192 + s];
    }
    if (qh >= 2){                      // m-slice loads, split across quarters 2,3
        float mz[2]={0,0}, mr[2]={0,0}, mh[2]={0,0};
        for (int sp = qh-2; sp < nsp; sp += 2){
            const float* Pp = part + ((size_t)sp*NN + n0)*384;
            #pragma unroll
            for (int j=0;j<2;j++){
                mz[j] += Pp[j*384 + s];
                mr[j] += Pp[j*384 + 128 + s];
                mh[j] += Pp[j*384 + 256 + s];
            }
        }
        int hh = qh - 2;
        redm[hh][0][0][s]=mz[0]; redm[hh][0][1][s]=mz[1];
        redm[hh][1][0][s]=mr[0]; redm[hh][1][1][s]=mr[1];
        redm[hh][2][0][s]=mh[0]; redm[hh][2][1][s]=mh[1];
    }
    __syncthreads();                   // xs ready for all quarters
    float dz[2]={0,0}, dr[2]={0,0};
    #pragma unroll 8
    for (int k=k0;k<k0+32;k++){
        float wz_ = uz[k*SECD + s], wr_ = ur[k*SECD + s];
        #pragma unroll
        for (int j=0;j<2;j++){ float xv = xs[j][k]; dz[j] += xv*wz_; dr[j] += xv*wr_; }
    }
    redz[qh][0][s]=dz[0]; redz[qh][1][s]=dz[1];
    redr[qh][0][s]=dr[0]; redr[qh][1][s]=dr[1];
    __syncthreads();
    float zz[2], rr[2];
    if (qh == 0){
        #pragma unroll
        for (int j=0;j<2;j++){
            float mzf = redm[0][0][j][s] + redm[1][0][j][s];
            float mrf = redm[0][1][j][s] + redm[1][1][j][s];
            float dzf = (redz[0][j][s]+redz[1][j][s]) + (redz[2][j][s]+redz[3][j][s]);
            float drf = (redr[0][j][s]+redr[1][j][s]) + (redr[2][j][s]+redr[3][j][s]);
            zz[j] = fsig(mzf + dzf + bz[s]);
            rr[j] = fsig(mrf + drf + br[s]);
            rx[j][s] = rr[j]*xs[j][s];
        }
    }
    __syncthreads();
    float dh[2]={0,0};
    #pragma unroll 8
    for (int k=k0;k<k0+32;k++){
        float wh_ = uh[k*SECD + s];
        #pragma unroll
        for (int j=0;j<2;j++) dh[j] += rx[j][k]*wh_;
    }
    redz[qh][0][s]=dh[0]; redz[qh][1][s]=dh[1];
    __syncthreads();
    if (qh == 0){
        #pragma unroll
        for (int j=0;j<2;j++){
            float mhf = redm[0][2][j][s] + redm[1][2][j][s];
            float dhf = (redz[0][j][s]+redz[1][j][s]) + (redz[2][j][s]+redz[3][j][s]);
            float hc = ftanh(mhf + dhf + bh[s]);
            x[(n0+j)*SS + 192 + s] = (1.f - zz[j])*xs[j][s] + rr[j]*hc;
        }
    }
}

// ---------------- nb = relu(nh @ gb_w + gb_b) -> nh2; 640 thr, k split -------------
__global__ __launch_bounds__(640) void k_gb(const float* __restrict__ nh,
                     const float* __restrict__ W,
                     const float* __restrict__ b, float* __restrict__ nb){
    int n0 = blockIdx.x*4;
    int tid = threadIdx.x;
    int h = (tid >= 320) ? 1 : 0;
    int s = tid - h*320;
    int k0 = h*160;
    __shared__ float xr_t[SS*4];                   // [k][j]
    __shared__ float red[2][4][SS];                // [half][note][col]
    if (h == 0){
        float v0 = nh[(n0+0)*SS + s], v1 = nh[(n0+1)*SS + s];
        float v2 = nh[(n0+2)*SS + s], v3 = nh[(n0+3)*SS + s];
        *(float4*)(xr_t + s*4) = make_float4(v0,v1,v2,v3);
    }
    __syncthreads();
    v2f a01={0.f,0.f}, a23={0.f,0.f};
    #pragma unroll 8
    for (int k=k0;k<k0+160;k++){
        float wv = W[k*SS + s];
        v2f ws = {wv, wv};
        const v2f* xp = (const v2f*)(xr_t + k*4);  // uniform addr -> broadcast
        pkfma(a01, xp[0], ws);
        pkfma(a23, xp[1], ws);
    }
    red[h][0][s]=a01.x; red[h][1][s]=a01.y; red[h][2][s]=a23.x; red[h][3][s]=a23.y;
    __syncthreads();
    if (h == 0){
        float bv = b[s];
        nb[(n0+0)*SS + s] = fmaxf(bv + red[0][0][s] + red[1][0][s], 0.f);
        nb[(n0+1)*SS + s] = fmaxf(bv + red[0][1][s] + red[1][1][s], 0.f);
        nb[(n0+2)*SS + s] = fmaxf(bv + red[0][2][s] + red[1][2][s], 0.f);
        nb[(n0+3)*SS + s] = fmaxf(bv + red[0][3][s] + red[1][3][s], 0.f);
    }
}

// ---------------- FUSED beat attention + lstm_pre, 512 thr, two-stage k-split ------
__global__ __launch_bounds__(512) void k_batt_fused(
        const float* __restrict__ nh, const float* __restrict__ nh2,
        const float* __restrict__ W, const float* __restrict__ b,
        const float* __restrict__ cvec,
        const float* __restrict__ wi_f, const float* __restrict__ b_f,
        const float* __restrict__ wi_b, const float* __restrict__ b_b,
        float* __restrict__ gf, float* __restrict__ gbo){
    int g = blockIdx.x;
    int tid = threadIdx.x;
    int s = tid & 255;                             // col
    int h = tid >> 8;                              // k-half (wave-uniform)
    __shared__ float xr_t[256*4];                  // [k][j]
    __shared__ float simw[4][8];
    __shared__ float wgt[4][8];
    __shared__ float bnode[256];
    __shared__ float red[2][4][256];               // [half][j][col] (reused)
    if (h == 0){
        float c0,c1,c2,c3;
        if (s < 128){
            c0 = nh[(g*4+0)*SS + 192 + s]; c1 = nh[(g*4+1)*SS + 192 + s];
            c2 = nh[(g*4+2)*SS + 192 + s]; c3 = nh[(g*4+3)*SS + 192 + s];
        } else {
            c0 = nh2[(g*4+0)*SS + 64 + s]; c1 = nh2[(g*4+1)*SS + 64 + s];
            c2 = nh2[(g*4+2)*SS + 64 + s]; c3 = nh2[(g*4+3)*SS + 64 + s];
        }
        *(float4*)(xr_t + s*4) = make_float4(c0,c1,c2,c3);
    }
    __syncthreads();
    {   // main GEMV: k-half per thread-half
        int k0 = h*128;
        v2f ac01 = {0.f,0.f}, ac23 = {0.f,0.f};
        #pragma unroll 8
        for (int k=k0;k<k0+128;k++){
            float wv = W[k*256 + s];
            v2f ws = {wv, wv};
            const v2f* xp = (const v2f*)(xr_t + k*4);
            pkfma(ac01, xp[0], ws);
            pkfma(ac23, xp[1], ws);
        }
        red[h][0][s]=ac01.x; red[h][1][s]=ac01.y; red[h][2][s]=ac23.x; red[h][3][s]=ac23.y;
    }
    __syncthreads();
    int hd = s >> 5;                               // head (HD=32)
    if (h == 0){
        float bias = b[s];
        float cv = cvec[s];
        #pragma unroll
        for (int j=0;j<4;j++){
            float p = ftanh(bias + red[0][j][s] + red[1][j][s])*cv;
            #pragma unroll
            for (int off=16; off>0; off>>=1) p += __shfl_down(p, off);
            if ((s & 31) == 0) simw[j][hd] = p;
        }
    }
    __syncthreads();
    if (tid < 8){
        float v0=simw[0][tid], v1=simw[1][tid], v2=simw[2][tid], v3=simw[3][tid];
        float mx = fmaxf(fmaxf(v0,v1), fmaxf(v2,v3));
        float e0=__expf(v0-mx), e1=__expf(v1-mx), e2=__expf(v2-mx), e3=__expf(v3-mx);
        float den = e0+e1+e2+e3;
        wgt[0][tid]=e0/den; wgt[1][tid]=e1/den; wgt[2][tid]=e2/den; wgt[3][tid]=e3/den;
    }
    __syncthreads();
    if (h == 0){
        float4 xs4 = *(const float4*)(xr_t + s*4);
        bnode[s] = xs4.x*wgt[0][hd] + xs4.y*wgt[1][hd] + xs4.z*wgt[2][hd] + xs4.w*wgt[3][hd];
    }
    __syncthreads();
    {   // pre-GEMV, both directions, k-half per thread-half
        v2f afA = {0.f,0.f}, afB = {0.f,0.f};
        v2f abA = {0.f,0.f}, abB = {0.f,0.f};
        const v2f* wfp = (const v2f*)(wi_f + (size_t)s*256);
        const v2f* wbp = (const v2f*)(wi_b + (size_t)s*256);
        const v2f* bp  = (const v2f*)bnode;
        int q0 = h*64;
        #pragma unroll 8
        for (int k2=q0;k2<q0+64;k2+=2){
            v2f x01 = bp[k2], x23 = bp[k2+1];
            pkfma(afA, wfp[k2], x01); pkfma(afB, wfp[k2+1], x23);
            pkfma(abA, wbp[k2], x01); pkfma(abB, wbp[k2+1], x23);
        }
        red[h][0][s] = (afA.x + afA.y) + (afB.x + afB.y);
        red[h][1][s] = (abA.x + abA.y) + (abB.x + abB.y);
    }
    __syncthreads();
    if (h == 0){
        gf [g*256 + s] = b_f[s] + red[0][0][s] + red[1][0][s];
        gbo[g*256 + s] = b_b[s] + red[0][1][s] + red[1][1][s];
    }
}

// ---------------- FUSED measure attention + lstm_pre, 256 thr, two-stage split -----
__global__ __launch_bounds__(256) void k_matt_fused(
        const float* __restrict__ bh,   // beat_hidden [256][128]
        const float* __restrict__ W, const float* __restrict__ b,
        const float* __restrict__ cvec,
        const float* __restrict__ wi_f, const float* __restrict__ b_f,
        const float* __restrict__ wi_b, const float* __restrict__ b_b,
        float* __restrict__ gf, float* __restrict__ gbo){
    int g = blockIdx.x;
    int tid = threadIdx.x;
    int s = tid & 127;                             // col
    int h = tid >> 7;                              // k-half (wave-uniform)
    __shared__ float xr_t[128*4];                  // [k][j]
    __shared__ float simw[4][8];
    __shared__ float wgt[4][8];
    __shared__ float mnode[128];
    __shared__ float red[2][4][128];               // [half][j][col] (reused)
    if (h == 0){
        float c0 = bh[(g*4+0)*128 + s], c1 = bh[(g*4+1)*128 + s];
        float c2 = bh[(g*4+2)*128 + s], c3 = bh[(g*4+3)*128 + s];
        *(float4*)(xr_t + s*4) = make_float4(c0,c1,c2,c3);
    }
    __syncthreads();
    {   // main GEMV: k-half per thread-half
        int k0 = h*64;
        v2f ac01 = {0.f,0.f}, ac23 = {0.f,0.f};
        #pragma unroll 8
        for (int k=k0;k<k0+64;k++){
            float wv = W[k*128 + s];
            v2f ws = {wv, wv};
            const v2f* xp = (const v2f*)(xr_t + k*4);
            pkfma(ac01, xp[0], ws);
            pkfma(ac23, xp[1], ws);
        }
        red[h][0][s]=ac01.x; red[h][1][s]=ac01.y; red[h][2][s]=ac23.x; red[h][3][s]=ac23.y;
    }
    __syncthreads();
    int hd = s >> 4;                               // head (HD=16)
    if (h == 0){
        float bias = b[s];
        float cv = cvec[s];
        #pragma unroll
        for (int j=0;j<4;j++){
            float p = ftanh(bias + red[0][j][s] + red[1][j][s])*cv;
            #pragma unroll
            for (int off=8; off>0; off>>=1) p += __shfl_down(p, off);
            if ((s & 15) == 0) simw[j][hd] = p;
        }
    }
    __syncthreads();
    if (tid < 8){
        float v0=simw[0][tid], v1=simw[1][tid], v2=simw[2][tid], v3=simw[3][tid];
        float mx = fmaxf(fmaxf(v0,v1), fmaxf(v2,v3));
        float e0=__expf(v0-mx), e1=__expf(v1-mx), e2=__expf(v2-mx), e3=__expf(v3-mx);
        float den = e0+e1+e2+e3;
        wgt[0][tid]=e0/den; wgt[1][tid]=e1/den; wgt[2][tid]=e2/den; wgt[3][tid]=e3/den;
    }
    __syncthreads();
    if (h == 0){
        float4 xs4 = *(const float4*)(xr_t + s*4);
        mnode[s] = xs4.x*wgt[0][hd] + xs4.y*wgt[1][hd] + xs4.z*wgt[2][hd] + xs4.w*wgt[3][hd];
    }
    __syncthreads();
    {   // pre-GEMV, both directions, k-half per thread-half
        v2f afA = {0.f,0.f}, afB = {0.f,0.f};
        v2f abA = {0.f,0.f}, abB = {0.f,0.f};
        const v2f* wfp = (const v2f*)(wi_f + (size_t)s*128);
        const v2f* wbp = (const v2f*)(wi_b + (size_t)s*128);
        const v2f* bp  = (const v2f*)mnode;
        int q0 = h*32;
        #pragma unroll 8
        for (int k2=q0;k2<q0+32;k2+=2){
            v2f x01 = bp[k2], x23 = bp[k2+1];
            pkfma(afA, wfp[k2], x01); pkfma(afB, wfp[k2+1], x23);
            pkfma(abA, wbp[k2], x01); pkfma(abB, wbp[k2+1], x23);
        }
        red[h][0][s] = (afA.x + afA.y) + (afB.x + afB.y);
        red[h][1][s] = (abA.x + abA.y) + (abB.x + abB.y);
    }
    __syncthreads();
    if (h == 0){
        gf [g*128 + s] = b_f[s] + red[0][0][s] + red[1][0][s];
        gbo[g*128 + s] = b_b[s] + red[0][1][s] + red[1][1][s];
    }
}

// ---------------- LSTM recurrence, H=64 T=256: frozen r14 form ---------------------
__global__ __launch_bounds__(256)
__attribute__((amdgpu_waves_per_eu(1, 1)))
void k_lstm_rec64(
        const float* __restrict__ gin_f, const float* __restrict__ wh_f,
        const float* __restrict__ gin_b, const float* __restrict__ wh_b,
        float* __restrict__ hid /* [T][128] */){
    const int H = 64, T = 256;
    int dir = blockIdx.x;
    const float* gin = dir ? gin_b : gin_f;
    const float* wh  = dir ? wh_b  : wh_f;
    int gi = threadIdx.x;
    int w  = gi >> 6;                      // wave
    int j  = gi & 63;                      // lane
    int o  = j & 15;                       // h offset within wave's range
    int g  = j >> 4;                       // gate (0=i,1=f,2=g,3=o)
    int l  = (w << 4) + o;                 // h index
    int row = (g << 6) + l;                // gate row in [0,256)
    const v2f* wp = (const v2f*)(wh + (size_t)row*H);
    v2f w00=wp[0], w01=wp[1], w02=wp[2], w03=wp[3], w04=wp[4], w05=wp[5], w06=wp[6], w07=wp[7],
        w08=wp[8], w09=wp[9], w10=wp[10],w11=wp[11],w12=wp[12],w13=wp[13],w14=wp[14],w15=wp[15],
        w16=wp[16],w17=wp[17],w18=wp[18],w19=wp[19],w20=wp[20],w21=wp[21],w22=wp[22],w23=wp[23],
        w24=wp[24],w25=wp[25],w26=wp[26],w27=wp[27],w28=wp[28],w29=wp[29],w30=wp[30],w31=wp[31];
    __shared__ __align__(16) float hsb[2][H];
    float c = 0.f;
    if (gi < H) hsb[0][gi] = 0.f;
    __syncthreads();
    const float* gp = gin + row;
    float gcur = gp[(dir ? (T-1) : 0)*256];
    for (int step=0; step<T; step++){
        int t = dir ? (T-1-step) : step;
        float gnext = 0.f;
        if (step+1 < T) gnext = gp[(dir ? (T-2-step) : (step+1))*256];
        const float4* hv = (const float4*)hsb[step & 1];   // uniform addr, b128
        float4 H0=hv[0],  H1=hv[1],  H2=hv[2],  H3=hv[3];
        float4 H4=hv[4],  H5=hv[5],  H6=hv[6],  H7=hv[7];
        float4 H8=hv[8],  H9=hv[9],  H10=hv[10],H11=hv[11];
        float4 H12=hv[12],H13=hv[13],H14=hv[14],H15=hv[15];
        v2f A0={gcur,0.f}, A1={0.f,0.f}, A2={0.f,0.f}, A3={0.f,0.f};
        pkfma(A0,w00,LO2(H0));  pkfma(A1,w01,HI2(H0));  pkfma(A2,w02,LO2(H1));  pkfma(A3,w03,HI2(H1));
        pkfma(A0,w04,LO2(H2));  pkfma(A1,w05,HI2(H2));  pkfma(A2,w06,LO2(H3));  pkfma(A3,w07,HI2(H3));
        pkfma(A0,w08,LO2(H4));  pkfma(A1,w09,HI2(H4));  pkfma(A2,w10,LO2(H5));  pkfma(A3,w11,HI2(H5));
        pkfma(A0,w12,LO2(H6));  pkfma(A1,w13,HI2(H6));  pkfma(A2,w14,LO2(H7));  pkfma(A3,w15,HI2(H7));
        pkfma(A0,w16,LO2(H8));  pkfma(A1,w17,HI2(H8));  pkfma(A2,w18,LO2(H9));  pkfma(A3,w19,HI2(H9));
        pkfma(A0,w20,LO2(H10)); pkfma(A1,w21,HI2(H10)); pkfma(A2,w22,LO2(H11)); pkfma(A3,w23,HI2(H11));
        pkfma(A0,w24,LO2(H12)); pkfma(A1,w25,HI2(H12)); pkfma(A2,w26,LO2(H13)); pkfma(A3,w27,HI2(H13));
        pkfma(A0,w28,LO2(H14)); pkfma(A1,w29,HI2(H14)); pkfma(A2,w30,LO2(H15)); pkfma(A3,w31,HI2(H15));
        float val = ((A0.x+A0.y) + (A1.x+A1.y)) + ((A2.x+A2.y) + (A3.x+A3.y));
        // intra-wave gate exchange: i/f/g/o for h=l live in lanes o, o+16, o+32, o+48
        float i_ = __shfl(val, o);
        float f_ = __shfl(val, o + 16);
        float g_ = __shfl(val, o + 32);
        float o_ = __shfl(val, o + 48);
        c = fsig(f_)*c + fsig(i_)*ftanh(g_);   // 4 lanes per l: identical update
        float hn = fsig(o_)*ftanh(c);
        if (g == 0){
            hsb[(step+1)&1][l] = hn;           // partitioned write, other buffer
            hid[t*2*H + dir*H + l] = hn;
        }
        __syncthreads();                       // the ONLY barrier per step
        gcur = gnext;
    }
}

// ---------------- LSTM recurrence, H=32 T=64: single wave, NO barrier --------------
__global__ __launch_bounds__(64)
__attribute__((amdgpu_waves_per_eu(1, 1)))
void k_lstm_rec32(
        const float* __restrict__ gin_f, const float* __restrict__ wh_f,
        const float* __restrict__ gin_b, const float* __restrict__ wh_b,
        float* __restrict__ hid /* [T][64] */){
    const int H = 32, T = 64;
    int dir = blockIdx.x;
    const float* gin = dir ? gin_b : gin_f;
    const float* wh  = dir ? wh_b  : wh_f;
    int gi = threadIdx.x;                  // 0..63
    v2f wA[16], wB[16];
    {
        const v2f* rA = (const v2f*)(wh + (size_t)(     gi)*H);   // rows 0..63:  i|f
        const v2f* rB = (const v2f*)(wh + (size_t)(64 + gi)*H);   // rows 64..127: g|o
        #pragma unroll
        for (int k=0;k<16;k++){ wA[k]=rA[k]; wB[k]=rB[k]; }
    }
    __shared__ __align__(16) float hs[H];
    float c = 0.f;
    if (gi < H) hs[gi] = 0.f;
    __syncthreads();
    const float* gp = gin + gi;
    int ts0 = dir ? (T-1) : 0, ts1 = dir ? (T-2) : 1;
    float g0 = gp[ts0*128], g1 = gp[ts0*128 + 64];
    float n0 = gp[ts1*128], n1 = gp[ts1*128 + 64];
    bool lo = (gi < H);
    for (int step=0; step<T; step++){
        int t = dir ? (T-1-step) : step;
        float p0=0.f, p1=0.f;
        if (step+2 < T){
            int tp = dir ? (T-3-step) : (step+2);
            p0 = gp[tp*128]; p1 = gp[tp*128 + 64];
        }
        v2f aA = {g0, 0.f}, aB = {g1, 0.f};
        const float4* hv = (const float4*)hs;      // uniform addr, b128 reads
        #pragma unroll
        for (int k=0;k<8;k++){
            float4 h4 = hv[k];
            pkfma(aA, wA[2*k],   LO2(h4));
            pkfma(aB, wB[2*k],   LO2(h4));
            pkfma(aA, wA[2*k+1], HI2(h4));
            pkfma(aB, wB[2*k+1], HI2(h4));
        }
        float sA = aA.x + aA.y;            // lane<32: i ; lane>=32: f
        float sB = aB.x + aB.y;            // lane<32: g ; lane>=32: o
        float pA = __shfl(sA, gi ^ 32);
        float pB = __shfl(sB, gi ^ 32);
        float i_ = lo ? sA : pA;
        float f_ = lo ? pA : sA;
        float g_ = lo ? sB : pB;
        float o_ = lo ? pB : sB;
        c = fsig(f_)*c + fsig(i_)*ftanh(g_);
        float hn = fsig(o_)*ftanh(c);
        if (lo){
            hid[t*2*H + dir*H + gi] = hn;
            hs[gi] = hn;                   // same wave: in-order LDS, no barrier
        }
        g0 = n0; g1 = n1; n0 = p0; n1 = p1;
    }
}

// ---------------- si=0: rebuild nh in place = [beat_span | meas_span | nh_sec] -----
__global__ void k_spans(float* __restrict__ nh, const float* __restrict__ bh,
                        const float* __restrict__ mh,
                        const int* __restrict__ bn, const int* __restrict__ mn){
    int n = blockIdx.x, s = threadIdx.x;           // 320 threads
    float v;
    if (s < 128)      v = bh[bn[n]*128 + s];
    else if (s < 192) v = mh[mn[n]*64 + (s-128)];
    else              v = nh[n*SS + s];            // own-thread read-then-write: safe
    nh[n*SS + s] = v;
}

// ---------------- si=1: spans + final output fused ---------------------------------
__global__ void k_spans_out(const float* __restrict__ bh, const float* __restrict__ mh,
                            const float* __restrict__ nh, const float* __restrict__ nh2,
                            const int* __restrict__ bn, const int* __restrict__ mn,
                            float* __restrict__ out){
    int n = blockIdx.x, s = threadIdx.x;           // 448 threads
    float v;
    if (s < 128)      v = bh[bn[n]*128 + s];
    else if (s < 192) v = mh[mn[n]*64 + (s-128)];
    else if (s < 320) v = nh[n*SS + s];
    else              v = nh2[n*SS + 192 + (s-320)];
    out[n*448 + s] = v;
}

// ===========================================================================
extern "C" void kernel_launch(void* const* d_in, const int* in_sizes, int n_in,
                              void* d_out, int out_size, void* d_ws, size_t ws_size,
                              hipStream_t stream) {
    const float* nodes    = (const float*)d_in[0];
    const float* adj      = (const float*)d_in[1];
    const int*   bn       = (const int*)  d_in[2];
    const int*   mn       = (const int*)  d_in[3];
    const float* fc_w     = (const float*)d_in[6];
    const float* fc_b     = (const float*)d_in[7];
    const float* g_wz[2]  = {(const float*)d_in[8],  (const float*)d_in[17]};
    const float* g_wr[2]  = {(const float*)d_in[9],  (const float*)d_in[18]};
    const float* g_wh[2]  = {(const float*)d_in[10], (const float*)d_in[19]};
    const float* g_uz[2]  = {(const float*)d_in[11], (const float*)d_in[20]};
    const float* g_ur[2]  = {(const float*)d_in[12], (const float*)d_in[21]};
    const float* g_uh[2]  = {(const float*)d_in[13], (const float*)d_in[22]};
    const float* g_bz[2]  = {(const float*)d_in[14], (const float*)d_in[23]};
    const float* g_br[2]  = {(const float*)d_in[15], (const float*)d_in[24]};
    const float* g_bh[2]  = {(const float*)d_in[16], (const float*)d_in[25]};
    const float* gb_w     = (const float*)d_in[26];
    const float* gb_b     = (const float*)d_in[27];
    const float* batt_w   = (const float*)d_in[28];
    const float* batt_b   = (const float*)d_in[29];
    const float* batt_c   = (const float*)d_in[30];
    const float* matt_w   = (const float*)d_in[31];
    const float* matt_b   = (const float*)d_in[32];
    const float* matt_c   = (const float*)d_in[33];
    const float* bwi_f    = (const float*)d_in[34];
    const float* bwh_f    = (const float*)d_in[35];
    const float* bb_f     = (const float*)d_in[36];
    const float* bwi_b    = (const float*)d_in[37];
    const float* bwh_b    = (const float*)d_in[38];
    const float* bb_b     = (const float*)d_in[39];
    const float* mwi_f    = (const float*)d_in[40];
    const float* mwh_f    = (const float*)d_in[41];
    const float* mb_f     = (const float*)d_in[42];
    const float* mwi_b    = (const float*)d_in[43];
    const float* mwh_b    = (const float*)d_in[44];
    const float* mb_b     = (const float*)d_in[45];
    float* out = (float*)d_out;

    // --- workspace layout (floats; ~27.7 MB, under the 31.2MB proven in r0) ---
    float* W_   = (float*)d_ws;
    float* nh   = W_;                       // 1024*320
    float* nh2  = nh   + 327680;            // 1024*320
    float* act  = nh2  + 327680;            // 10*1024*320
    float* part = act  + 3276800;           // 10*1024*384 (slices 0-4 dyn, 5-9 static)
    float* bgf  = part + 3932160;           // 256*256
    float* bgb  = bgf  + 65536;             // 256*256
    float* beat_hidden = bgb + 65536;       // 256*128
    float* mgf  = beat_hidden + 32768;      // 64*128
    float* mgb  = mgf  + 8192;              // 64*128
    float* meas_hidden = mgb + 8192;        // 64*64
    int*   cnt  = (int*)(meas_hidden + 4096);  // 10*1024
    int*   idx  = cnt + 10240;                  // 10*1024*64

    float* part_s = part + 5*NN*384;        // static slices base (contiguous: 5-9)

    hipMemsetAsync(cnt, 0, EE*NN*sizeof(int), stream);
    k_csr_build<<<EE*NN, 256, 0, stream>>>(adj, cnt, idx);
    k_note_fc<<<NN, 128, 0, stream>>>(nodes, fc_w, fc_b, nh);

    for (int si = 0; si < 2; ++si){
        for (int half = 0; half < 2; ++half){
            float* x = half ? nh2 : nh;
            int w = half;                     // weight set index
            bool zerostatic = (si == 0 && half == 0);   // nh[:, :192] == 0
            if (half == 1)                    // nb = relu(nh @ gb_w) -> nh2
                k_gb<<<NN/4, 640, 0, stream>>>(nh, gb_w, gb_b, nh2);
            for (int it = 0; it < 2; ++it){
                if (!zerostatic && it == 0){
                    // one full 320-col gather; static+dyn gemms in ONE launch
                    k_gather_full<<<EE*NN/4, 320, 0, stream>>>(x, cnt, idx, act);
                    k_gate_gemm_both<<<dim3(32,6,5), 256, 0, stream>>>(
                            act, g_wz[w], g_wr[w], g_wh[w], part, part_s);
                } else {
                    k_gather_dyn<<<EE*NN/8, 256, 0, stream>>>(x, cnt, idx, act);
                    // it=1 (or zerostatic): dyn gemm, fold static via addv when present
                    k_gate_gemm_dyn<<<dim3(32,3,5), 256, 0, stream>>>(
                            act, g_wz[w], g_wr[w], g_wh[w], part,
                            zerostatic ? nullptr : part_s);
                }
                int nsp = (!zerostatic && it == 0) ? 10 : 5;
                k_gru<<<NN/2, 512, 0, stream>>>(x, part, nsp,
                        g_uz[w], g_ur[w], g_uh[w], g_bz[w], g_br[w], g_bh[w]);
            }
        }
        k_batt_fused<<<NB, 512, 0, stream>>>(nh, nh2, batt_w, batt_b, batt_c,
                                             bwi_f, bb_f, bwi_b, bb_b, bgf, bgb);
        k_lstm_rec64<<<2, 256, 0, stream>>>(bgf, bwh_f, bgb, bwh_b, beat_hidden);
        k_matt_fused<<<NM, 256, 0, stream>>>(beat_hidden, matt_w, matt_b, matt_c,
                                             mwi_f, mb_f, mwi_b, mb_b, mgf, mgb);
        k_lstm_rec32<<<2, 64, 0, stream>>>(mgf, mwh_f, mgb, mwh_b, meas_hidden);
        if (si == 0)
            k_spans<<<NN, SS, 0, stream>>>(nh, beat_hidden, meas_hidden, bn, mn);
        else
            k_spans_out<<<NN, 448, 0, stream>>>(beat_hidden, meas_hidden, nh, nh2,
                                                bn, mn, out);
    }
}

// Round 17
// 918.421 us; speedup vs baseline: 1.0181x; 1.0181x over previous
//
#include <hip/hip_runtime.h>
#include <math.h>

// ---------------------------------------------------------------------------
// IsgnBeatMeasEncoder — round 21: REVERT round-20 (B-DMA-first staging hurt:
// 919 -> 935). The compiler was already overlapping A/B issue; forcing B
// first pushed A's ds_write behind 4 in-order DMA completions and lengthened
// the pre-barrier tail (guide rule: don't out-schedule hipcc at source level).
// This file is the round-19 kernel verbatim — the session best (919us, from
// 1622us baseline = -43%). All mechanisms measured to their floors:
//   rec64: 116us latency floor (4 structural attempts), frozen.
//   gemm: DMA-staged, static/dyn split, merged it=0 launch.
//   gru: 4-quarter k-split, m-loads off critical path.
//   gathers: LDS list cache + 4-way prefetch de-chaining.
//   gb/batt/matt: wave-aligned k-split + LDS reduce.
// ---------------------------------------------------------------------------

#define NN    1024
#define EE    10
#define INDIM 78
#define SS    320
#define SECD  128
#define NB    256
#define NM    64
#define CAP   64     // max nonzeros per adjacency column (mean ~10.2)

typedef float v2f __attribute__((ext_vector_type(2)));

__device__ __forceinline__ void pkfma(v2f& a, v2f x, v2f y){
    asm("v_pk_fma_f32 %0, %1, %2, %0" : "+v"(a) : "v"(x), "v"(y));
}
// a.lo += x.lo*b.lo ; a.hi += x.hi*b.lo   (broadcast LOW half of b)
__device__ __forceinline__ void pkfma_blo(v2f& a, v2f x, v2f b){
    asm("v_pk_fma_f32 %0, %1, %2, %0 op_sel:[0,0,0] op_sel_hi:[1,0,1]"
        : "+v"(a) : "v"(x), "v"(b));
}
// a.lo += x.lo*b.hi ; a.hi += x.hi*b.hi   (broadcast HIGH half of b)
__device__ __forceinline__ void pkfma_bhi(v2f& a, v2f x, v2f b){
    asm("v_pk_fma_f32 %0, %1, %2, %0 op_sel:[0,1,0] op_sel_hi:[1,1,1]"
        : "+v"(a) : "v"(x), "v"(b));
}

#define LO2(F) ((v2f){F.x, F.y})
#define HI2(F) ((v2f){F.z, F.w})

__device__ __forceinline__ float fsig(float x){
    return __builtin_amdgcn_rcpf(1.f + __expf(-x));
}
__device__ __forceinline__ float ftanh(float x){
    // tanh(x) = 1 - 2/(exp(2x)+1); exp overflow -> inf -> rcp -> 0 -> 1 (correct)
    return 1.f - 2.f*__builtin_amdgcn_rcpf(1.f + __expf(2.f*x));
}

// ---------------- note_fc: x0 = tanh(nodes @ W + b); nh = [0(192) | x0] ------------
__global__ void k_note_fc(const float* __restrict__ nodes, const float* __restrict__ W,
                          const float* __restrict__ b, float* __restrict__ nh){
    int n = blockIdx.x, s = threadIdx.x;           // 128 threads
    __shared__ float xrow[INDIM];
    if (s < INDIM) xrow[s] = nodes[n*INDIM + s];
    __syncthreads();
    float acc = b[s];
    for (int k = 0; k < INDIM; ++k) acc += xrow[k]*W[k*128 + s];
    nh[n*SS + 192 + s] = ftanh(acc);
    nh[n*SS + s] = 0.f;
    if (s < 64) nh[n*SS + 128 + s] = 0.f;
}

// ---------------- CSR build: float4 scan of each adj row ---------------------------
__global__ void k_csr_build(const float* __restrict__ adj, int* __restrict__ cnt,
                            int* __restrict__ idx){
    int em = blockIdx.x;                   // e*NN + m  (row of adj[e])
    int e = em / NN, m = em % NN;
    const float4* row4 = (const float4*)(adj + (size_t)em * NN);
    int q = threadIdx.x;                   // 256 threads, 256 float4 = 1024 cols
    float4 v = row4[q];
    int n0 = q*4;
    if (v.x != 0.f){ int p = atomicAdd(&cnt[e*NN + n0+0], 1); if (p < CAP) idx[((size_t)e*NN + n0+0)*CAP + p] = m; }
    if (v.y != 0.f){ int p = atomicAdd(&cnt[e*NN + n0+1], 1); if (p < CAP) idx[((size_t)e*NN + n0+1)*CAP + p] = m; }
    if (v.z != 0.f){ int p = atomicAdd(&cnt[e*NN + n0+2], 1); if (p < CAP) idx[((size_t)e*NN + n0+2)*CAP + p] = m; }
    if (v.w != 0.f){ int p = atomicAdd(&cnt[e*NN + n0+3], 1); if (p < CAP) idx[((size_t)e*NN + n0+3)*CAP + p] = m; }
}

// ---------------- full gather (320 cols): LDS list cache + 4-way prefetch ----------
// 4 en/block, 320 threads (80 quads per en).
__global__ void k_gather_full(const float* __restrict__ x, const int* __restrict__ cnt,
                              const int* __restrict__ idx, float* __restrict__ act){
    int tid = threadIdx.x;
    int eg = tid / 80;                     // en group 0..3
    int q  = tid % 80;
    int en = blockIdx.x*4 + eg;
    __shared__ int lst_l[4][CAP];
    int c = cnt[en]; if (c > CAP) c = CAP; // same addr per group -> broadcast
    for (int j = q; j < c; j += 80) lst_l[eg][j] = idx[(size_t)en*CAP + j];
    __syncthreads();
    float4 acc = {0.f,0.f,0.f,0.f};
    const float* xb = x + q*4;
    int j = 0;
    for (; j + 4 <= c; j += 4){            // 4 independent loads in flight
        int m0=lst_l[eg][j], m1=lst_l[eg][j+1], m2=lst_l[eg][j+2], m3=lst_l[eg][j+3];
        float4 v0 = *(const float4*)(xb + (size_t)m0*SS);
        float4 v1 = *(const float4*)(xb + (size_t)m1*SS);
        float4 v2 = *(const float4*)(xb + (size_t)m2*SS);
        float4 v3 = *(const float4*)(xb + (size_t)m3*SS);
        acc.x += (v0.x+v1.x)+(v2.x+v3.x);
        acc.y += (v0.y+v1.y)+(v2.y+v3.y);
        acc.z += (v0.z+v1.z)+(v2.z+v3.z);
        acc.w += (v0.w+v1.w)+(v2.w+v3.w);
    }
    for (; j < c; ++j){
        float4 v = *(const float4*)(xb + (size_t)lst_l[eg][j]*SS);
        acc.x += v.x; acc.y += v.y; acc.z += v.z; acc.w += v.w;
    }
    *(float4*)(act + (size_t)en*SS + q*4) = acc;
}

// ---------------- dyn gather (cols 192..320): LDS list cache + 4-way prefetch ------
// 8 en/block, 256 threads (32 quads per en).
__global__ void k_gather_dyn(const float* __restrict__ x, const int* __restrict__ cnt,
                             const int* __restrict__ idx, float* __restrict__ act){
    int tid = threadIdx.x;
    int eg = tid >> 5;                     // en group 0..7
    int q  = tid & 31;
    int en = blockIdx.x*8 + eg;
    __shared__ int lst_l[8][CAP];
    int c = cnt[en]; if (c > CAP) c = CAP;
    for (int j = q; j < c; j += 32) lst_l[eg][j] = idx[(size_t)en*CAP + j];
    __syncthreads();
    float4 acc = {0.f,0.f,0.f,0.f};
    const float* xb = x + 192 + q*4;
    int j = 0;
    for (; j + 4 <= c; j += 4){
        int m0=lst_l[eg][j], m1=lst_l[eg][j+1], m2=lst_l[eg][j+2], m3=lst_l[eg][j+3];
        float4 v0 = *(const float4*)(xb + (size_t)m0*SS);
        float4 v1 = *(const float4*)(xb + (size_t)m1*SS);
        float4 v2 = *(const float4*)(xb + (size_t)m2*SS);
        float4 v3 = *(const float4*)(xb + (size_t)m3*SS);
        acc.x += (v0.x+v1.x)+(v2.x+v3.x);
        acc.y += (v0.y+v1.y)+(v2.y+v3.y);
        acc.z += (v0.z+v1.z)+(v2.z+v3.z);
        acc.w += (v0.w+v1.w)+(v2.w+v3.w);
    }
    for (; j < c; ++j){
        float4 v = *(const float4*)(xb + (size_t)lst_l[eg][j]*SS);
        acc.x += v.x; acc.y += v.y; acc.z += v.z; acc.w += v.w;
    }
    *(float4*)(act + (size_t)en*SS + 192 + q*4) = acc;
}

// ---------------- gate GEMM core (runtime K range) ---------------------------------
// B LDS layout: LINEAR stride 128 (no pad) -> staging via global_load_lds:
// per wave, global src and LDS dest are both wave-uniform + lane*16B.
// A staged first (compiler overlaps issue), then B DMAs — r19-proven order.
__device__ __forceinline__ void gemm_body(const float* __restrict__ act,
        const float* __restrict__ W, float* __restrict__ outp,
        const float* __restrict__ addv, int K0, int K1, int nt, int z,
        float* A, float* B){
    int tid = threadIdx.x;
    int tx = tid & 31;             // cols tx*4 .. +3
    int ty = tid >> 5;             // rows ty*4 .. +3
    v2f acc[2][4];
    #pragma unroll
    for (int i=0;i<2;i++)
        #pragma unroll
        for (int j=0;j<4;j++) acc[i][j] = (v2f){0.f,0.f};
    for (int eh = 0; eh < 2; ++eh){
        int e = z*2 + eh;
        const float* Ae = act + (size_t)e*NN*SS + (size_t)nt*32*SS;
        const float* We = W   + (size_t)e*SS*SECD;
        for (int kc = K0; kc < K1; kc += 32){
            {                                      // A: 32 rows x 32 k = 256 float4
                int r  = tid >> 3;
                int k4 = (tid & 7) << 2;
                float4 v = *(const float4*)(Ae + r*SS + kc + k4);
                A[(k4+0)*36 + r] = v.x; A[(k4+1)*36 + r] = v.y;
                A[(k4+2)*36 + r] = v.z; A[(k4+3)*36 + r] = v.w;
            }
            #pragma unroll
            for (int i=0;i<4;i++){                 // B: 32 k x 128 cols, DMA to LDS
                int lin4 = tid + i*256;            // float4 index; linear in LDS
                __builtin_amdgcn_global_load_lds(
                    (const __attribute__((address_space(1))) unsigned int*)
                        (We + (size_t)kc*SECD + (size_t)lin4*4),
                    (__attribute__((address_space(3))) unsigned int*)(B + lin4*4),
                    16, 0, 0);
            }
            __syncthreads();                       // drains vmcnt+lgkm (B, A ready)
            #pragma unroll 8
            for (int k=0;k<32;k++){
                float4 a4 = *(const float4*)(A + k*36 + ty*4);   // wave-uniform b128
                v2f a01 = LO2(a4), a23 = HI2(a4);
                float4 b = *(const float4*)(B + k*128 + tx*4);
                v2f b01 = {b.x, b.y}, b23 = {b.z, b.w};
                pkfma_blo(acc[0][0], a01, b01); pkfma_bhi(acc[0][1], a01, b01);
                pkfma_blo(acc[0][2], a01, b23); pkfma_bhi(acc[0][3], a01, b23);
                pkfma_blo(acc[1][0], a23, b01); pkfma_bhi(acc[1][1], a23, b01);
                pkfma_blo(acc[1][2], a23, b23); pkfma_bhi(acc[1][3], a23, b23);
            }
            __syncthreads();
        }
    }
    size_t base = ((size_t)z*NN + (size_t)nt*32)*384;   // +g*SECD folded by caller
    float* P = outp + base;
    int r0 = ty*4;
    float4 o0 = make_float4(acc[0][0].x, acc[0][1].x, acc[0][2].x, acc[0][3].x);
    float4 o1 = make_float4(acc[0][0].y, acc[0][1].y, acc[0][2].y, acc[0][3].y);
    float4 o2 = make_float4(acc[1][0].x, acc[1][1].x, acc[1][2].x, acc[1][3].x);
    float4 o3 = make_float4(acc[1][0].y, acc[1][1].y, acc[1][2].y, acc[1][3].y);
    if (addv){
        const float* Q = addv + base;
        float4 q0 = *(const float4*)(Q + (size_t)(r0+0)*384 + tx*4);
        float4 q1 = *(const float4*)(Q + (size_t)(r0+1)*384 + tx*4);
        float4 q2 = *(const float4*)(Q + (size_t)(r0+2)*384 + tx*4);
        float4 q3 = *(const float4*)(Q + (size_t)(r0+3)*384 + tx*4);
        o0.x+=q0.x; o0.y+=q0.y; o0.z+=q0.z; o0.w+=q0.w;
        o1.x+=q1.x; o1.y+=q1.y; o1.z+=q1.z; o1.w+=q1.w;
        o2.x+=q2.x; o2.y+=q2.y; o2.z+=q2.z; o2.w+=q2.w;
        o3.x+=q3.x; o3.y+=q3.y; o3.z+=q3.z; o3.w+=q3.w;
    }
    *(float4*)(P + (size_t)(r0+0)*384 + tx*4) = o0;
    *(float4*)(P + (size_t)(r0+1)*384 + tx*4) = o1;
    *(float4*)(P + (size_t)(r0+2)*384 + tx*4) = o2;
    *(float4*)(P + (size_t)(r0+3)*384 + tx*4) = o3;
}

// dyn-only (with optional addv fold): grid (32,3,5)
__global__ __launch_bounds__(256) void k_gate_gemm_dyn(const float* __restrict__ act,
        const float* __restrict__ wz, const float* __restrict__ wr,
        const float* __restrict__ wh, float* __restrict__ part,
        const float* __restrict__ addv){
    __shared__ float A[32*36];
    __shared__ float B[32*128];
    int g = blockIdx.y;
    const float* W = (g==0) ? wz : ((g==1) ? wr : wh);
    const float* av = addv ? (addv + g*SECD) : nullptr;
    gemm_body(act, W, part + g*SECD, av, 192, 320, blockIdx.x, blockIdx.z, A, B);
}

// merged it=0: static (y<3 -> part_s, K 0..192) + dyn (y>=3 -> part, K 192..320),
// grid (32,6,5), no addv (gru reads 10 slices this iteration).
__global__ __launch_bounds__(256) void k_gate_gemm_both(const float* __restrict__ act,
        const float* __restrict__ wz, const float* __restrict__ wr,
        const float* __restrict__ wh, float* __restrict__ part,
        float* __restrict__ part_s){
    __shared__ float A[32*36];
    __shared__ float B[32*128];
    int y = blockIdx.y;            // 0..5
    int g = (y >= 3) ? (y - 3) : y;
    const float* W = (g==0) ? wz : ((g==1) ? wr : wh);
    if (y >= 3)
        gemm_body(act, W, part   + g*SECD, nullptr, 192, 320, blockIdx.x, blockIdx.z, A, B);
    else
        gemm_body(act, W, part_s + g*SECD, nullptr,   0, 192, blockIdx.x, blockIdx.z, A, B);
}

// ---------------- GRU update v3: 512 thr, 2 notes, k split across 4 quarters -------
__global__ __launch_bounds__(512) void k_gru(float* __restrict__ x,
        const float* __restrict__ part, int nsp,
        const float* __restrict__ uz, const float* __restrict__ ur, const float* __restrict__ uh,
        const float* __restrict__ bz, const float* __restrict__ br, const float* __restrict__ bh){
    int n0 = blockIdx.x*2;
    int tid = threadIdx.x;
    int s  = tid & 127;                // col
    int qh = tid >> 7;                 // quarter (wave-uniform)
    int k0 = qh*32;
    __shared__ float xs[2][SECD], rx[2][SECD];
    __shared__ float redz[4][2][SECD], redr[4][2][SECD];   // redz reused for dh
    __shared__ float redm[2][3][2][SECD];                  // [half][gate][note][col]
    if (qh == 0){
        xs[0][s] = x[(n0+0)*SS + 192 + s];
        xs[1][s] = x[(n0+1)*SS + 192 + s];
    }
    if (qh >= 2){                      // m-slice loads, split across quarters 2,3
        float mz[2]={0,0}, mr[2]={0,0}, mh[2]={0,0};
        for (int sp = qh-2; sp < nsp; sp += 2){
            const float* Pp = part + ((size_t)sp*NN + n0)*384;
            #pragma unroll
            for (int j=0;j<2;j++){
                mz[j] += Pp[j*384 + s];
                mr[j] += Pp[j*384 + 128 + s];
                mh[j] += Pp[j*384 + 256 + s];
            }
        }
        int hh = qh - 2;
        redm[hh][0][0][s]=mz[0]; redm[hh][0][1][s]=mz[1];
        redm[hh][1][0][s]=mr[0]; redm[hh][1][1][s]=mr[1];
        redm[hh][2][0][s]=mh[0]; redm[hh][2][1][s]=mh[1];
    }
    __syncthreads();                   // xs ready for all quarters
    float dz[2]={0,0}, dr[2]={0,0};
    #pragma unroll 8
    for (int k=k0;k<k0+32;k++){
        float wz_ = uz[k*SECD + s], wr_ = ur[k*SECD + s];
        #pragma unroll
        for (int j=0;j<2;j++){ float xv = xs[j][k]; dz[j] += xv*wz_; dr[j] += xv*wr_; }
    }
    redz[qh][0][s]=dz[0]; redz[qh][1][s]=dz[1];
    redr[qh][0][s]=dr[0]; redr[qh][1][s]=dr[1];
    __syncthreads();
    float zz[2], rr[2];
    if (qh == 0){
        #pragma unroll
        for (int j=0;j<2;j++){
            float mzf = redm[0][0][j][s] + redm[1][0][j][s];
            float mrf = redm[0][1][j][s] + redm[1][1][j][s];
            float dzf = (redz[0][j][s]+redz[1][j][s]) + (redz[2][j][s]+redz[3][j][s]);
            float drf = (redr[0][j][s]+redr[1][j][s]) + (redr[2][j][s]+redr[3][j][s]);
            zz[j] = fsig(mzf + dzf + bz[s]);
            rr[j] = fsig(mrf + drf + br[s]);
            rx[j][s] = rr[j]*xs[j][s];
        }
    }
    __syncthreads();
    float dh[2]={0,0};
    #pragma unroll 8
    for (int k=k0;k<k0+32;k++){
        float wh_ = uh[k*SECD + s];
        #pragma unroll
        for (int j=0;j<2;j++) dh[j] += rx[j][k]*wh_;
    }
    redz[qh][0][s]=dh[0]; redz[qh][1][s]=dh[1];
    __syncthreads();
    if (qh == 0){
        #pragma unroll
        for (int j=0;j<2;j++){
            float mhf = redm[0][2][j][s] + redm[1][2][j][s];
            float dhf = (redz[0][j][s]+redz[1][j][s]) + (redz[2][j][s]+redz[3][j][s]);
            float hc = ftanh(mhf + dhf + bh[s]);
            x[(n0+j)*SS + 192 + s] = (1.f - zz[j])*xs[j][s] + rr[j]*hc;
        }
    }
}

// ---------------- nb = relu(nh @ gb_w + gb_b) -> nh2; 640 thr, k split -------------
__global__ __launch_bounds__(640) void k_gb(const float* __restrict__ nh,
                     const float* __restrict__ W,
                     const float* __restrict__ b, float* __restrict__ nb){
    int n0 = blockIdx.x*4;
    int tid = threadIdx.x;
    int h = (tid >= 320) ? 1 : 0;
    int s = tid - h*320;
    int k0 = h*160;
    __shared__ float xr_t[SS*4];                   // [k][j]
    __shared__ float red[2][4][SS];                // [half][note][col]
    if (h == 0){
        float v0 = nh[(n0+0)*SS + s], v1 = nh[(n0+1)*SS + s];
        float v2 = nh[(n0+2)*SS + s], v3 = nh[(n0+3)*SS + s];
        *(float4*)(xr_t + s*4) = make_float4(v0,v1,v2,v3);
    }
    __syncthreads();
    v2f a01={0.f,0.f}, a23={0.f,0.f};
    #pragma unroll 8
    for (int k=k0;k<k0+160;k++){
        float wv = W[k*SS + s];
        v2f ws = {wv, wv};
        const v2f* xp = (const v2f*)(xr_t + k*4);  // uniform addr -> broadcast
        pkfma(a01, xp[0], ws);
        pkfma(a23, xp[1], ws);
    }
    red[h][0][s]=a01.x; red[h][1][s]=a01.y; red[h][2][s]=a23.x; red[h][3][s]=a23.y;
    __syncthreads();
    if (h == 0){
        float bv = b[s];
        nb[(n0+0)*SS + s] = fmaxf(bv + red[0][0][s] + red[1][0][s], 0.f);
        nb[(n0+1)*SS + s] = fmaxf(bv + red[0][1][s] + red[1][1][s], 0.f);
        nb[(n0+2)*SS + s] = fmaxf(bv + red[0][2][s] + red[1][2][s], 0.f);
        nb[(n0+3)*SS + s] = fmaxf(bv + red[0][3][s] + red[1][3][s], 0.f);
    }
}

// ---------------- FUSED beat attention + lstm_pre, 512 thr, two-stage k-split ------
__global__ __launch_bounds__(512) void k_batt_fused(
        const float* __restrict__ nh, const float* __restrict__ nh2,
        const float* __restrict__ W, const float* __restrict__ b,
        const float* __restrict__ cvec,
        const float* __restrict__ wi_f, const float* __restrict__ b_f,
        const float* __restrict__ wi_b, const float* __restrict__ b_b,
        float* __restrict__ gf, float* __restrict__ gbo){
    int g = blockIdx.x;
    int tid = threadIdx.x;
    int s = tid & 255;                             // col
    int h = tid >> 8;                              // k-half (wave-uniform)
    __shared__ float xr_t[256*4];                  // [k][j]
    __shared__ float simw[4][8];
    __shared__ float wgt[4][8];
    __shared__ float bnode[256];
    __shared__ float red[2][4][256];               // [half][j][col] (reused)
    if (h == 0){
        float c0,c1,c2,c3;
        if (s < 128){
            c0 = nh[(g*4+0)*SS + 192 + s]; c1 = nh[(g*4+1)*SS + 192 + s];
            c2 = nh[(g*4+2)*SS + 192 + s]; c3 = nh[(g*4+3)*SS + 192 + s];
        } else {
            c0 = nh2[(g*4+0)*SS + 64 + s]; c1 = nh2[(g*4+1)*SS + 64 + s];
            c2 = nh2[(g*4+2)*SS + 64 + s]; c3 = nh2[(g*4+3)*SS + 64 + s];
        }
        *(float4*)(xr_t + s*4) = make_float4(c0,c1,c2,c3);
    }
    __syncthreads();
    {   // main GEMV: k-half per thread-half
        int k0 = h*128;
        v2f ac01 = {0.f,0.f}, ac23 = {0.f,0.f};
        #pragma unroll 8
        for (int k=k0;k<k0+128;k++){
            float wv = W[k*256 + s];
            v2f ws = {wv, wv};
            const v2f* xp = (const v2f*)(xr_t + k*4);
            pkfma(ac01, xp[0], ws);
            pkfma(ac23, xp[1], ws);
        }
        red[h][0][s]=ac01.x; red[h][1][s]=ac01.y; red[h][2][s]=ac23.x; red[h][3][s]=ac23.y;
    }
    __syncthreads();
    int hd = s >> 5;                               // head (HD=32)
    if (h == 0){
        float bias = b[s];
        float cv = cvec[s];
        #pragma unroll
        for (int j=0;j<4;j++){
            float p = ftanh(bias + red[0][j][s] + red[1][j][s])*cv;
            #pragma unroll
            for (int off=16; off>0; off>>=1) p += __shfl_down(p, off);
            if ((s & 31) == 0) simw[j][hd] = p;
        }
    }
    __syncthreads();
    if (tid < 8){
        float v0=simw[0][tid], v1=simw[1][tid], v2=simw[2][tid], v3=simw[3][tid];
        float mx = fmaxf(fmaxf(v0,v1), fmaxf(v2,v3));
        float e0=__expf(v0-mx), e1=__expf(v1-mx), e2=__expf(v2-mx), e3=__expf(v3-mx);
        float den = e0+e1+e2+e3;
        wgt[0][tid]=e0/den; wgt[1][tid]=e1/den; wgt[2][tid]=e2/den; wgt[3][tid]=e3/den;
    }
    __syncthreads();
    if (h == 0){
        float4 xs4 = *(const float4*)(xr_t + s*4);
        bnode[s] = xs4.x*wgt[0][hd] + xs4.y*wgt[1][hd] + xs4.z*wgt[2][hd] + xs4.w*wgt[3][hd];
    }
    __syncthreads();
    {   // pre-GEMV, both directions, k-half per thread-half
        v2f afA = {0.f,0.f}, afB = {0.f,0.f};
        v2f abA = {0.f,0.f}, abB = {0.f,0.f};
        const v2f* wfp = (const v2f*)(wi_f + (size_t)s*256);
        const v2f* wbp = (const v2f*)(wi_b + (size_t)s*256);
        const v2f* bp  = (const v2f*)bnode;
        int q0 = h*64;
        #pragma unroll 8
        for (int k2=q0;k2<q0+64;k2+=2){
            v2f x01 = bp[k2], x23 = bp[k2+1];
            pkfma(afA, wfp[k2], x01); pkfma(afB, wfp[k2+1], x23);
            pkfma(abA, wbp[k2], x01); pkfma(abB, wbp[k2+1], x23);
        }
        red[h][0][s] = (afA.x + afA.y) + (afB.x + afB.y);
        red[h][1][s] = (abA.x + abA.y) + (abB.x + abB.y);
    }
    __syncthreads();
    if (h == 0){
        gf [g*256 + s] = b_f[s] + red[0][0][s] + red[1][0][s];
        gbo[g*256 + s] = b_b[s] + red[0][1][s] + red[1][1][s];
    }
}

// ---------------- FUSED measure attention + lstm_pre, 256 thr, two-stage split -----
__global__ __launch_bounds__(256) void k_matt_fused(
        const float* __restrict__ bh,   // beat_hidden [256][128]
        const float* __restrict__ W, const float* __restrict__ b,
        const float* __restrict__ cvec,
        const float* __restrict__ wi_f, const float* __restrict__ b_f,
        const float* __restrict__ wi_b, const float* __restrict__ b_b,
        float* __restrict__ gf, float* __restrict__ gbo){
    int g = blockIdx.x;
    int tid = threadIdx.x;
    int s = tid & 127;                             // col
    int h = tid >> 7;                              // k-half (wave-uniform)
    __shared__ float xr_t[128*4];                  // [k][j]
    __shared__ float simw[4][8];
    __shared__ float wgt[4][8];
    __shared__ float mnode[128];
    __shared__ float red[2][4][128];               // [half][j][col] (reused)
    if (h == 0){
        float c0 = bh[(g*4+0)*128 + s], c1 = bh[(g*4+1)*128 + s];
        float c2 = bh[(g*4+2)*128 + s], c3 = bh[(g*4+3)*128 + s];
        *(float4*)(xr_t + s*4) = make_float4(c0,c1,c2,c3);
    }
    __syncthreads();
    {   // main GEMV: k-half per thread-half
        int k0 = h*64;
        v2f ac01 = {0.f,0.f}, ac23 = {0.f,0.f};
        #pragma unroll 8
        for (int k=k0;k<k0+64;k++){
            float wv = W[k*128 + s];
            v2f ws = {wv, wv};
            const v2f* xp = (const v2f*)(xr_t + k*4);
            pkfma(ac01, xp[0], ws);
            pkfma(ac23, xp[1], ws);
        }
        red[h][0][s]=ac01.x; red[h][1][s]=ac01.y; red[h][2][s]=ac23.x; red[h][3][s]=ac23.y;
    }
    __syncthreads();
    int hd = s >> 4;                               // head (HD=16)
    if (h == 0){
        float bias = b[s];
        float cv = cvec[s];
        #pragma unroll
        for (int j=0;j<4;j++){
            float p = ftanh(bias + red[0][j][s] + red[1][j][s])*cv;
            #pragma unroll
            for (int off=8; off>0; off>>=1) p += __shfl_down(p, off);
            if ((s & 15) == 0) simw[j][hd] = p;
        }
    }
    __syncthreads();
    if (tid < 8){
        float v0=simw[0][tid], v1=simw[1][tid], v2=simw[2][tid], v3=simw[3][tid];
        float mx = fmaxf(fmaxf(v0,v1), fmaxf(v2,v3));
        float e0=__expf(v0-mx), e1=__expf(v1-mx), e2=__expf(v2-mx), e3=__expf(v3-mx);
        float den = e0+e1+e2+e3;
        wgt[0][tid]=e0/den; wgt[1][tid]=e1/den; wgt[2][tid]=e2/den; wgt[3][tid]=e3/den;
    }
    __syncthreads();
    if (h == 0){
        float4 xs4 = *(const float4*)(xr_t + s*4);
        mnode[s] = xs4.x*wgt[0][hd] + xs4.y*wgt[1][hd] + xs4.z*wgt[2][hd] + xs4.w*wgt[3][hd];
    }
    __syncthreads();
    {   // pre-GEMV, both directions, k-half per thread-half
        v2f afA = {0.f,0.f}, afB = {0.f,0.f};
        v2f abA = {0.f,0.f}, abB = {0.f,0.f};
        const v2f* wfp = (const v2f*)(wi_f + (size_t)s*128);
        const v2f* wbp = (const v2f*)(wi_b + (size_t)s*128);
        const v2f* bp  = (const v2f*)mnode;
        int q0 = h*32;
        #pragma unroll 8
        for (int k2=q0;k2<q0+32;k2+=2){
            v2f x01 = bp[k2], x23 = bp[k2+1];
            pkfma(afA, wfp[k2], x01); pkfma(afB, wfp[k2+1], x23);
            pkfma(abA, wbp[k2], x01); pkfma(abB, wbp[k2+1], x23);
        }
        red[h][0][s] = (afA.x + afA.y) + (afB.x + afB.y);
        red[h][1][s] = (abA.x + abA.y) + (abB.x + abB.y);
    }
    __syncthreads();
    if (h == 0){
        gf [g*128 + s] = b_f[s] + red[0][0][s] + red[1][0][s];
        gbo[g*128 + s] = b_b[s] + red[0][1][s] + red[1][1][s];
    }
}

// ---------------- LSTM recurrence, H=64 T=256: frozen r14 form ---------------------
__global__ __launch_bounds__(256)
__attribute__((amdgpu_waves_per_eu(1, 1)))
void k_lstm_rec64(
        const float* __restrict__ gin_f, const float* __restrict__ wh_f,
        const float* __restrict__ gin_b, const float* __restrict__ wh_b,
        float* __restrict__ hid /* [T][128] */){
    const int H = 64, T = 256;
    int dir = blockIdx.x;
    const float* gin = dir ? gin_b : gin_f;
    const float* wh  = dir ? wh_b  : wh_f;
    int gi = threadIdx.x;
    int w  = gi >> 6;                      // wave
    int j  = gi & 63;                      // lane
    int o  = j & 15;                       // h offset within wave's range
    int g  = j >> 4;                       // gate (0=i,1=f,2=g,3=o)
    int l  = (w << 4) + o;                 // h index
    int row = (g << 6) + l;                // gate row in [0,256)
    const v2f* wp = (const v2f*)(wh + (size_t)row*H);
    v2f w00=wp[0], w01=wp[1], w02=wp[2], w03=wp[3], w04=wp[4], w05=wp[5], w06=wp[6], w07=wp[7],
        w08=wp[8], w09=wp[9], w10=wp[10],w11=wp[11],w12=wp[12],w13=wp[13],w14=wp[14],w15=wp[15],
        w16=wp[16],w17=wp[17],w18=wp[18],w19=wp[19],w20=wp[20],w21=wp[21],w22=wp[22],w23=wp[23],
        w24=wp[24],w25=wp[25],w26=wp[26],w27=wp[27],w28=wp[28],w29=wp[29],w30=wp[30],w31=wp[31];
    __shared__ __align__(16) float hsb[2][H];
    float c = 0.f;
    if (gi < H) hsb[0][gi] = 0.f;
    __syncthreads();
    const float* gp = gin + row;
    float gcur = gp[(dir ? (T-1) : 0)*256];
    for (int step=0; step<T; step++){
        int t = dir ? (T-1-step) : step;
        float gnext = 0.f;
        if (step+1 < T) gnext = gp[(dir ? (T-2-step) : (step+1))*256];
        const float4* hv = (const float4*)hsb[step & 1];   // uniform addr, b128
        float4 H0=hv[0],  H1=hv[1],  H2=hv[2],  H3=hv[3];
        float4 H4=hv[4],  H5=hv[5],  H6=hv[6],  H7=hv[7];
        float4 H8=hv[8],  H9=hv[9],  H10=hv[10],H11=hv[11];
        float4 H12=hv[12],H13=hv[13],H14=hv[14],H15=hv[15];
        v2f A0={gcur,0.f}, A1={0.f,0.f}, A2={0.f,0.f}, A3={0.f,0.f};
        pkfma(A0,w00,LO2(H0));  pkfma(A1,w01,HI2(H0));  pkfma(A2,w02,LO2(H1));  pkfma(A3,w03,HI2(H1));
        pkfma(A0,w04,LO2(H2));  pkfma(A1,w05,HI2(H2));  pkfma(A2,w06,LO2(H3));  pkfma(A3,w07,HI2(H3));
        pkfma(A0,w08,LO2(H4));  pkfma(A1,w09,HI2(H4));  pkfma(A2,w10,LO2(H5));  pkfma(A3,w11,HI2(H5));
        pkfma(A0,w12,LO2(H6));  pkfma(A1,w13,HI2(H6));  pkfma(A2,w14,LO2(H7));  pkfma(A3,w15,HI2(H7));
        pkfma(A0,w16,LO2(H8));  pkfma(A1,w17,HI2(H8));  pkfma(A2,w18,LO2(H9));  pkfma(A3,w19,HI2(H9));
        pkfma(A0,w20,LO2(H10)); pkfma(A1,w21,HI2(H10)); pkfma(A2,w22,LO2(H11)); pkfma(A3,w23,HI2(H11));
        pkfma(A0,w24,LO2(H12)); pkfma(A1,w25,HI2(H12)); pkfma(A2,w26,LO2(H13)); pkfma(A3,w27,HI2(H13));
        pkfma(A0,w28,LO2(H14)); pkfma(A1,w29,HI2(H14)); pkfma(A2,w30,LO2(H15)); pkfma(A3,w31,HI2(H15));
        float val = ((A0.x+A0.y) + (A1.x+A1.y)) + ((A2.x+A2.y) + (A3.x+A3.y));
        // intra-wave gate exchange: i/f/g/o for h=l live in lanes o, o+16, o+32, o+48
        float i_ = __shfl(val, o);
        float f_ = __shfl(val, o + 16);
        float g_ = __shfl(val, o + 32);
        float o_ = __shfl(val, o + 48);
        c = fsig(f_)*c + fsig(i_)*ftanh(g_);   // 4 lanes per l: identical update
        float hn = fsig(o_)*ftanh(c);
        if (g == 0){
            hsb[(step+1)&1][l] = hn;           // partitioned write, other buffer
            hid[t*2*H + dir*H + l] = hn;
        }
        __syncthreads();                       // the ONLY barrier per step
        gcur = gnext;
    }
}

// ---------------- LSTM recurrence, H=32 T=64: single wave, NO barrier --------------
__global__ __launch_bounds__(64)
__attribute__((amdgpu_waves_per_eu(1, 1)))
void k_lstm_rec32(
        const float* __restrict__ gin_f, const float* __restrict__ wh_f,
        const float* __restrict__ gin_b, const float* __restrict__ wh_b,
        float* __restrict__ hid /* [T][64] */){
    const int H = 32, T = 64;
    int dir = blockIdx.x;
    const float* gin = dir ? gin_b : gin_f;
    const float* wh  = dir ? wh_b  : wh_f;
    int gi = threadIdx.x;                  // 0..63
    v2f wA[16], wB[16];
    {
        const v2f* rA = (const v2f*)(wh + (size_t)(     gi)*H);   // rows 0..63:  i|f
        const v2f* rB = (const v2f*)(wh + (size_t)(64 + gi)*H);   // rows 64..127: g|o
        #pragma unroll
        for (int k=0;k<16;k++){ wA[k]=rA[k]; wB[k]=rB[k]; }
    }
    __shared__ __align__(16) float hs[H];
    float c = 0.f;
    if (gi < H) hs[gi] = 0.f;
    __syncthreads();
    const float* gp = gin + gi;
    int ts0 = dir ? (T-1) : 0, ts1 = dir ? (T-2) : 1;
    float g0 = gp[ts0*128], g1 = gp[ts0*128 + 64];
    float n0 = gp[ts1*128], n1 = gp[ts1*128 + 64];
    bool lo = (gi < H);
    for (int step=0; step<T; step++){
        int t = dir ? (T-1-step) : step;
        float p0=0.f, p1=0.f;
        if (step+2 < T){
            int tp = dir ? (T-3-step) : (step+2);
            p0 = gp[tp*128]; p1 = gp[tp*128 + 64];
        }
        v2f aA = {g0, 0.f}, aB = {g1, 0.f};
        const float4* hv = (const float4*)hs;      // uniform addr, b128 reads
        #pragma unroll
        for (int k=0;k<8;k++){
            float4 h4 = hv[k];
            pkfma(aA, wA[2*k],   LO2(h4));
            pkfma(aB, wB[2*k],   LO2(h4));
            pkfma(aA, wA[2*k+1], HI2(h4));
            pkfma(aB, wB[2*k+1], HI2(h4));
        }
        float sA = aA.x + aA.y;            // lane<32: i ; lane>=32: f
        float sB = aB.x + aB.y;            // lane<32: g ; lane>=32: o
        float pA = __shfl(sA, gi ^ 32);
        float pB = __shfl(sB, gi ^ 32);
        float i_ = lo ? sA : pA;
        float f_ = lo ? pA : sA;
        float g_ = lo ? sB : pB;
        float o_ = lo ? pB : sB;
        c = fsig(f_)*c + fsig(i_)*ftanh(g_);
        float hn = fsig(o_)*ftanh(c);
        if (lo){
            hid[t*2*H + dir*H + gi] = hn;
            hs[gi] = hn;                   // same wave: in-order LDS, no barrier
        }
        g0 = n0; g1 = n1; n0 = p0; n1 = p1;
    }
}

// ---------------- si=0: rebuild nh in place = [beat_span | meas_span | nh_sec] -----
__global__ void k_spans(float* __restrict__ nh, const float* __restrict__ bh,
                        const float* __restrict__ mh,
                        const int* __restrict__ bn, const int* __restrict__ mn){
    int n = blockIdx.x, s = threadIdx.x;           // 320 threads
    float v;
    if (s < 128)      v = bh[bn[n]*128 + s];
    else if (s < 192) v = mh[mn[n]*64 + (s-128)];
    else              v = nh[n*SS + s];            // own-thread read-then-write: safe
    nh[n*SS + s] = v;
}

// ---------------- si=1: spans + final output fused ---------------------------------
__global__ void k_spans_out(const float* __restrict__ bh, const float* __restrict__ mh,
                            const float* __restrict__ nh, const float* __restrict__ nh2,
                            const int* __restrict__ bn, const int* __restrict__ mn,
                            float* __restrict__ out){
    int n = blockIdx.x, s = threadIdx.x;           // 448 threads
    float v;
    if (s < 128)      v = bh[bn[n]*128 + s];
    else if (s < 192) v = mh[mn[n]*64 + (s-128)];
    else if (s < 320) v = nh[n*SS + s];
    else              v = nh2[n*SS + 192 + (s-320)];
    out[n*448 + s] = v;
}

// ===========================================================================
extern "C" void kernel_launch(void* const* d_in, const int* in_sizes, int n_in,
                              void* d_out, int out_size, void* d_ws, size_t ws_size,
                              hipStream_t stream) {
    const float* nodes    = (const float*)d_in[0];
    const float* adj      = (const float*)d_in[1];
    const int*   bn       = (const int*)  d_in[2];
    const int*   mn       = (const int*)  d_in[3];
    const float* fc_w     = (const float*)d_in[6];
    const float* fc_b     = (const float*)d_in[7];
    const float* g_wz[2]  = {(const float*)d_in[8],  (const float*)d_in[17]};
    const float* g_wr[2]  = {(const float*)d_in[9],  (const float*)d_in[18]};
    const float* g_wh[2]  = {(const float*)d_in[10], (const float*)d_in[19]};
    const float* g_uz[2]  = {(const float*)d_in[11], (const float*)d_in[20]};
    const float* g_ur[2]  = {(const float*)d_in[12], (const float*)d_in[21]};
    const float* g_uh[2]  = {(const float*)d_in[13], (const float*)d_in[22]};
    const float* g_bz[2]  = {(const float*)d_in[14], (const float*)d_in[23]};
    const float* g_br[2]  = {(const float*)d_in[15], (const float*)d_in[24]};
    const float* g_bh[2]  = {(const float*)d_in[16], (const float*)d_in[25]};
    const float* gb_w     = (const float*)d_in[26];
    const float* gb_b     = (const float*)d_in[27];
    const float* batt_w   = (const float*)d_in[28];
    const float* batt_b   = (const float*)d_in[29];
    const float* batt_c   = (const float*)d_in[30];
    const float* matt_w   = (const float*)d_in[31];
    const float* matt_b   = (const float*)d_in[32];
    const float* matt_c   = (const float*)d_in[33];
    const float* bwi_f    = (const float*)d_in[34];
    const float* bwh_f    = (const float*)d_in[35];
    const float* bb_f     = (const float*)d_in[36];
    const float* bwi_b    = (const float*)d_in[37];
    const float* bwh_b    = (const float*)d_in[38];
    const float* bb_b     = (const float*)d_in[39];
    const float* mwi_f    = (const float*)d_in[40];
    const float* mwh_f    = (const float*)d_in[41];
    const float* mb_f     = (const float*)d_in[42];
    const float* mwi_b    = (const float*)d_in[43];
    const float* mwh_b    = (const float*)d_in[44];
    const float* mb_b     = (const float*)d_in[45];
    float* out = (float*)d_out;

    // --- workspace layout (floats; ~27.7 MB, under the 31.2MB proven in r0) ---
    float* W_   = (float*)d_ws;
    float* nh   = W_;                       // 1024*320
    float* nh2  = nh   + 327680;            // 1024*320
    float* act  = nh2  + 327680;            // 10*1024*320
    float* part = act  + 3276800;           // 10*1024*384 (slices 0-4 dyn, 5-9 static)
    float* bgf  = part + 3932160;           // 256*256
    float* bgb  = bgf  + 65536;             // 256*256
    float* beat_hidden = bgb + 65536;       // 256*128
    float* mgf  = beat_hidden + 32768;      // 64*128
    float* mgb  = mgf  + 8192;              // 64*128
    float* meas_hidden = mgb + 8192;        // 64*64
    int*   cnt  = (int*)(meas_hidden + 4096);  // 10*1024
    int*   idx  = cnt + 10240;                  // 10*1024*64

    float* part_s = part + 5*NN*384;        // static slices base (contiguous: 5-9)

    hipMemsetAsync(cnt, 0, EE*NN*sizeof(int), stream);
    k_csr_build<<<EE*NN, 256, 0, stream>>>(adj, cnt, idx);
    k_note_fc<<<NN, 128, 0, stream>>>(nodes, fc_w, fc_b, nh);

    for (int si = 0; si < 2; ++si){
        for (int half = 0; half < 2; ++half){
            float* x = half ? nh2 : nh;
            int w = half;                     // weight set index
            bool zerostatic = (si == 0 && half == 0);   // nh[:, :192] == 0
            if (half == 1)                    // nb = relu(nh @ gb_w) -> nh2
                k_gb<<<NN/4, 640, 0, stream>>>(nh, gb_w, gb_b, nh2);
            for (int it = 0; it < 2; ++it){
                if (!zerostatic && it == 0){
                    // one full 320-col gather; static+dyn gemms in ONE launch
                    k_gather_full<<<EE*NN/4, 320, 0, stream>>>(x, cnt, idx, act);
                    k_gate_gemm_both<<<dim3(32,6,5), 256, 0, stream>>>(
                            act, g_wz[w], g_wr[w], g_wh[w], part, part_s);
                } else {
                    k_gather_dyn<<<EE*NN/8, 256, 0, stream>>>(x, cnt, idx, act);
                    // it=1 (or zerostatic): dyn gemm, fold static via addv when present
                    k_gate_gemm_dyn<<<dim3(32,3,5), 256, 0, stream>>>(
                            act, g_wz[w], g_wr[w], g_wh[w], part,
                            zerostatic ? nullptr : part_s);
                }
                int nsp = (!zerostatic && it == 0) ? 10 : 5;
                k_gru<<<NN/2, 512, 0, stream>>>(x, part, nsp,
                        g_uz[w], g_ur[w], g_uh[w], g_bz[w], g_br[w], g_bh[w]);
            }
        }
        k_batt_fused<<<NB, 512, 0, stream>>>(nh, nh2, batt_w, batt_b, batt_c,
                                             bwi_f, bb_f, bwi_b, bb_b, bgf, bgb);
        k_lstm_rec64<<<2, 256, 0, stream>>>(bgf, bwh_f, bgb, bwh_b, beat_hidden);
        k_matt_fused<<<NM, 256, 0, stream>>>(beat_hidden, matt_w, matt_b, matt_c,
                                             mwi_f, mb_f, mwi_b, mb_b, mgf, mgb);
        k_lstm_rec32<<<2, 64, 0, stream>>>(mgf, mwh_f, mgb, mwh_b, meas_hidden);
        if (si == 0)
            k_spans<<<NN, SS, 0, stream>>>(nh, beat_hidden, meas_hidden, bn, mn);
        else
            k_spans_out<<<NN, 448, 0, stream>>>(beat_hidden, meas_hidden, nh, nh2,
                                                bn, mn, out);
    }
}